// Round 8
// baseline (186.390 us; speedup 1.0000x reference)
//
#include <hip/hip_runtime.h>

#define LOG2PI 1.8378770664093453

__device__ __forceinline__ float rl32(float v, int l) {
  return __int_as_float(__builtin_amdgcn_readlane(__float_as_int(v), l));
}

// One (b,p) instance per 128-thread block, two cooperative waves.
// r7 lesson: memory traffic is off the critical path (FETCH 33MB, WRITE 8.7MB,
// HBM 3.8%); the kernel is latency/serial-bound (VALUBusy 40%, Occ 42%).
// This round: COLUMN-split the P1/P4 Gram phases across all 128 threads
// (each thread owns a (row, col-strip) and runs the full g=0..63 loop) ->
// no partial buffers, no merge phases, 2 fewer barriers, LDS 14.3->11.5KB
// -> 13 blocks x 2 waves = 26 waves/CU for latency hiding.
// Phase 1 (QR on A + projection): sign-free -> Gram + Cholesky + solves (f32).
// Phase 2 (QR on PB; LAPACK signs matter): compressed Householder recursion
// on (Gram(PB,Pc) 17x17, top-16 rows of [PB|Pc]); beta = -sign(alpha)*norm.
__global__ __launch_bounds__(128, 6) void cint_kernel(
    const float* __restrict__ input_i,
    const float* __restrict__ Prev_coefs,
    const float* __restrict__ Prev_biases,
    const float* __restrict__ LPin,
    const float* __restrict__ Log_factors,
    const float* __restrict__ obs_var,
    const float* __restrict__ hid_var,
    const float* __restrict__ nxt_var,
    const float* __restrict__ rec_biases,
    float* __restrict__ out,
    int NBP)
{
  __shared__ float X[64*36];   // [A(16)|B(16)|c(1)|pad] rows, stride 36
  __shared__ float S[16*36];   // S_AA|S_AB|S_Ac (cols 0..32), col33=1/Ljj;
                               // cols 16..32 overwritten by W; reused as G
  __shared__ float M2[2];      // [0]=||Pc||^2, [1]=LC1

  const int tid  = threadIdx.x;
  const int w    = tid >> 6;
  const int lane = tid & 63;
  const int bid  = blockIdx.x;
  const int inst = (bid & 7) * (NBP >> 3) + (bid >> 3);  // XCD-chunked swizzle

  float* PB = X;    // after P3: [64][20], cols 0..15 PB, 16 Pc
  float* G  = S;    // after P4: [16][18] Gram of [PB|Pc] (overlays dead S)

  const size_t NB_OFFv = (size_t)NBP * 256;
  const size_t LP_OFFv = NB_OFFv + (size_t)NBP * 16;

  const float lp_lf = LPin[inst] + Log_factors[inst];

  // ---------------- P0: stage X = [A | B | c]; w0->A, w1->B/c --------------
  {
    const int g = lane;
    const size_t rowidx = (g < 16) ? ((size_t)g * NBP + inst)
                                   : ((size_t)(g - 16) * NBP + inst);
    if (w == 0) {
      const float* aptr = (g < 16) ? (Prev_coefs + rowidx * 16)
                                   : (hid_var    + rowidx * 16);
      *(float4*)&X[g*36 +  0] = *(const float4*)(aptr + 0);
      *(float4*)&X[g*36 +  4] = *(const float4*)(aptr + 4);
      *(float4*)&X[g*36 +  8] = *(const float4*)(aptr + 8);
      *(float4*)&X[g*36 + 12] = *(const float4*)(aptr + 12);
    } else {
      float4 z4 = make_float4(0.f, 0.f, 0.f, 0.f);
      float4 b0 = z4, b1 = z4, b2 = z4, b3 = z4;
      float cv;
      if (g < 16) {
        cv = Prev_biases[rowidx];
      } else {
        const float* bptr = nxt_var + rowidx * 16;
        b0 = *(const float4*)(bptr + 0);
        b1 = *(const float4*)(bptr + 4);
        b2 = *(const float4*)(bptr + 8);
        b3 = *(const float4*)(bptr + 12);
        float4 ob = *(const float4*)(obs_var + rowidx * 4);
        float4 iv = *(const float4*)(input_i + (size_t)inst * 4);
        cv = rec_biases[rowidx] + ob.x*iv.x + ob.y*iv.y + ob.z*iv.z + ob.w*iv.w;
      }
      *(float4*)&X[g*36 + 16] = b0;
      *(float4*)&X[g*36 + 20] = b1;
      *(float4*)&X[g*36 + 24] = b2;
      *(float4*)&X[g*36 + 28] = b3;
      X[g*36 + 32] = cv;
    }
  }
  __syncthreads();

  // ------- P1 column-split: S[i][4st..4st+3] (+col32 for st==0), full g ----
  {
    const int i  = tid & 15;
    const int st = tid >> 4;      // 0..7 -> cols 4st..4st+3
    float ac0=0, ac1=0, ac2=0, ac3=0, ac4=0;
    #pragma unroll 8
    for (int g = 0; g < 64; ++g) {
      const float* xr = &X[g*36];
      float  xi = xr[i];
      float4 cv = *(const float4*)(xr + 4*st);
      ac0 = fmaf(xi, cv.x, ac0);
      ac1 = fmaf(xi, cv.y, ac1);
      ac2 = fmaf(xi, cv.z, ac2);
      ac3 = fmaf(xi, cv.w, ac3);
      if (st == 0) ac4 = fmaf(xi, xr[32], ac4);
    }
    float* srow = &S[i*36 + 4*st];
    srow[0]=ac0; srow[1]=ac1; srow[2]=ac2; srow[3]=ac3;
    if (st == 0) S[i*36 + 32] = ac4;
  }
  __syncthreads();

  // ---------------- P2 (wave0 only): Cholesky + 17-RHS solve ---------------
  if (w == 0) {
    float Lr[16];
    {
      const int ir = lane & 15;
      double prodd = 1.0;
      #pragma unroll
      for (int j = 0; j < 16; ++j) {
        float s = S[ir*36 + j];
        #pragma unroll
        for (int m = 0; m < j; ++m) s = fmaf(-Lr[m], rl32(Lr[m], j), s);
        float sj = rl32(s, j);
        sj = fmaxf(sj, 1e-30f);
        float Ljj = sqrtf(sj);
        float iv  = 1.0f / Ljj;
        prodd *= (double)sj;
        Lr[j] = (ir == j) ? Ljj : s * iv;
        if (lane == j) S[j*36 + 33] = iv;   // stash 1/L_jj
      }
      if (lane == 0) M2[1] = (float)(-0.5 * log(prodd));  // LC1
    }
    {
      const int rc = (lane < 17) ? lane : 16;
      float x[16];
      #pragma unroll
      for (int j = 0; j < 16; ++j) {
        float t = S[j*36 + 16 + rc];
        #pragma unroll
        for (int m = 0; m < j; ++m) t = fmaf(-rl32(Lr[m], j), x[m], t);
        x[j] = t * S[j*36 + 33];
      }
      #pragma unroll
      for (int j = 15; j >= 0; --j) {
        float t = x[j];
        #pragma unroll
        for (int m = j + 1; m < 16; ++m) t = fmaf(-rl32(Lr[j], m), x[m], t);
        x[j] = t * S[j*36 + 33];
      }
      if (lane < 17) {                       // W overwrites S_AB/S_Ac region
        #pragma unroll
        for (int m = 0; m < 16; ++m) S[m*36 + 16 + lane] = x[m];
      }
    }
  }
  __syncthreads();

  // ---------------- P3: PB = B - A*W (column-split), Pc, ||Pc||^2 ----------
  {
    const int g = lane;
    const float* xr = &X[g*36];
    float4 a0 = *(const float4*)(xr + 0);
    float4 a1 = *(const float4*)(xr + 4);
    float4 a2 = *(const float4*)(xr + 8);
    float4 a3 = *(const float4*)(xr + 12);
    float ad[16] = { a0.x,a0.y,a0.z,a0.w, a1.x,a1.y,a1.z,a1.w,
                     a2.x,a2.y,a2.z,a2.w, a3.x,a3.y,a3.z,a3.w };
    // wave0 owns logical cols 0..7, wave1 owns 8..16 (incl Pc)
    float4 e0, e1; float pc = 0.0f;
    if (w == 0) {
      e0 = *(const float4*)(xr + 16);
      e1 = *(const float4*)(xr + 20);
    } else {
      e0 = *(const float4*)(xr + 24);
      e1 = *(const float4*)(xr + 28);
      pc = xr[32];
    }
    float pb[8] = { e0.x,e0.y,e0.z,e0.w, e1.x,e1.y,e1.z,e1.w };
    __syncthreads();                 // ALL X reads done before PB overwrites
    const int coff = 16 + 8*w;       // W col base for this wave
    #pragma unroll
    for (int m = 0; m < 16; ++m) {
      float am = ad[m];
      float4 w0v = *(const float4*)(&S[m*36 + coff]);
      float4 w1v = *(const float4*)(&S[m*36 + coff + 4]);
      pb[0] = fmaf(-am, w0v.x, pb[0]); pb[1] = fmaf(-am, w0v.y, pb[1]);
      pb[2] = fmaf(-am, w0v.z, pb[2]); pb[3] = fmaf(-am, w0v.w, pb[3]);
      pb[4] = fmaf(-am, w1v.x, pb[4]); pb[5] = fmaf(-am, w1v.y, pb[5]);
      pb[6] = fmaf(-am, w1v.z, pb[6]); pb[7] = fmaf(-am, w1v.w, pb[7]);
      if (w == 1) pc = fmaf(-am, S[m*36 + 32], pc);
    }
    if (w == 1) {                    // ||Pc||^2 reduce within wave1
      float q = pc * pc;
      #pragma unroll
      for (int msk = 1; msk < 64; msk <<= 1) q += __shfl_xor(q, msk, 64);
      if (lane == 0) M2[0] = q;
    }
    float4 o0 = { pb[0], pb[1], pb[2], pb[3] };
    float4 o1 = { pb[4], pb[5], pb[6], pb[7] };
    *(float4*)&PB[g*20 + 8*w + 0] = o0;
    *(float4*)&PB[g*20 + 8*w + 4] = o1;
    if (w == 1) PB[g*20 + 16] = pc;
  }
  __syncthreads();

  // ------- P4 column-split: G[k1][2q,2q+1] (+col16 for q==0), full g -------
  // G overlays S (W dead after P3). Stride 18.
  {
    const int k1 = tid & 15;
    const int q  = tid >> 4;      // 0..7 -> cols 2q, 2q+1
    float ac0=0, ac1=0, ac4=0;
    #pragma unroll 8
    for (int g = 0; g < 64; ++g) {
      const float* pr = &PB[g*20];
      float  xr = pr[k1];
      float2 cv = *(const float2*)(pr + 2*q);
      ac0 = fmaf(xr, cv.x, ac0);
      ac1 = fmaf(xr, cv.y, ac1);
      if (q == 0) ac4 = fmaf(xr, pr[16], ac4);
    }
    // overlay write: G row k1 occupies floats [k1*18, k1*18+17] of S
    G[k1*18 + 2*q]     = ac0;
    G[k1*18 + 2*q + 1] = ac1;
    if (q == 0) G[k1*18 + 16] = ac4;
  }
  __syncthreads();

  // ---------------- P5 (wave0 only): compressed Householder QR2 ------------
  if (w == 0) {
    const int k  = lane;
    const int kc = (k < 17) ? k : 16;   // lane k owns column k (16 = Pc)
    float Tr[16];
    float Gh[16];
    #pragma unroll
    for (int r = 0; r < 16; ++r) Tr[r] = PB[r*20 + kc];
    #pragma unroll
    for (int j = 0; j < 16; ++j) Gh[j] = G[j*18 + kc];
    float nbacc = 0.0f;
    #pragma unroll
    for (int j = 0; j < 16; ++j) {
      float alf  = rl32(Tr[j], j);           // alpha = T[j][j]
      float nrm2 = rl32(Gh[j], j);           // ||active col j||^2
      float nrm  = sqrtf(fmaxf(nrm2, 1e-30f));
      float aa   = fabsf(alf);
      float tau  = 1.0f + aa / nrm;          // (beta-alpha)/beta
      float inv  = copysignf(1.0f / (aa + nrm), alf);  // 1/(alpha-beta)
      float beta = -copysignf(nrm, alf);     // LAPACK R_jj
      float Tj   = Tr[j];
      float wv   = Tj + (Gh[j] - alf * Tj) * inv;      // v^T col_k
      float Rv   = Tj - tau * wv;                      // R[j][k], k>=j
      if (k < 16) {
        float ov = (k < j) ? 0.0f : ((k == j) ? beta : Rv);
        out[((size_t)j * NBP + inst) * 16 + k] = ov;   // Next_coefs
      } else if (k == 16) {
        out[NB_OFFv + (size_t)j * NBP + inst] = Rv;    // Next_biases
        nbacc = fmaf(Rv, Rv, nbacc);
      }
      float twi = tau * wv * inv;
      #pragma unroll
      for (int r = j + 1; r < 16; ++r) {     // T update (rows > j)
        float vr = rl32(Tr[r], j);
        Tr[r] = fmaf(-twi, vr, Tr[r]);
      }
      #pragma unroll
      for (int l = j + 1; l < 16; ++l) {     // Ghat -= R_j outer R_j
        float Rl = rl32(Rv, l);
        Gh[l] = fmaf(-Rl, Rv, Gh[l]);
      }
    }
    if (k == 16) {
      double resid = fmax((double)M2[0] - (double)nbacc, 0.0);
      double LC = (double)M2[1] - 0.5 * (32.0 * LOG2PI + resid);
      out[LP_OFFv + (size_t)inst] = lp_lf + (float)LC;
    }
  }
}

extern "C" void kernel_launch(void* const* d_in, const int* in_sizes, int n_in,
                              void* d_out, int out_size, void* d_ws, size_t ws_size,
                              hipStream_t stream) {
  (void)n_in; (void)out_size; (void)d_ws; (void)ws_size;
  const int NBP = in_sizes[3];              // B*P (LP element count) = 8192
  cint_kernel<<<NBP, 128, 0, stream>>>(
      (const float*)d_in[0], (const float*)d_in[1], (const float*)d_in[2],
      (const float*)d_in[3], (const float*)d_in[4], (const float*)d_in[5],
      (const float*)d_in[6], (const float*)d_in[7], (const float*)d_in[8],
      (float*)d_out, NBP);
}

// Round 9
// 176.955 us; speedup vs baseline: 1.0533x; 1.0533x over previous
//
#include <hip/hip_runtime.h>

#define LOG2PI 1.8378770664093453

__device__ __forceinline__ float rl32(float v, int l) {
  return __int_as_float(__builtin_amdgcn_readlane(__float_as_int(v), l));
}

// Schur-complement pipeline, one (b,p) instance per 128-thread block (2 waves).
//   M33 = Gram([A|B|c]) (33x33 lower-tri)          [cooperative]
//   L11 = chol(S_AA); LC1 = -sum log L11_jj        [wave0 serial, 16 steps]
//   fwd-solve L11*[Y|Z] = [S_ABc | A_top^T] 33 RHS [wave0, ONE forward pass]
//   Ghat = S_BBc - Y^T Y ; T = [0|c_top] - Z^T Y   [cooperative 16-deep]
//   P5: compressed Householder sign recursion on (Ghat, T) -- unchanged from
//       r8 (proven): beta=-sign(alpha)*nrm, R row j streams to global.
// Identities: W never formed (backward solve deleted); PB never materialized
// (P3/P4 deleted); B_top=0 because prev-Gaussians have zero next-var coefs.
// LDS float-offset map (single buffer, phase-overlaid):
//  [0,2304)    X[64][36]   staged [A|B|c] rows (cols 33..35 zeroed)
//  [0,1188)    M33[33][36] Gram lower-tri (overlays X after X dies)
//  [1188,1508) STAB[16][20] STAB[j][k]=S_ABc[j][k]; later T[r][k] (same slot)
//  [1508,1828) Y[16][20]   Y[m][k]
//  [1828,2148) Z[16][20]   Z[m][r]
//  [2148,2454) G[17][18]   Ghat
//  [2454,2470) CTOP[16]
//  [2470,2790) ATOPT[16][20] ATOPT[m][r]=A_top[r][m]
//  [2790,2792) M2: [1]=LC1
#define OFF_M33   0
#define OFF_STAB  1188
#define OFF_T     1188
#define OFF_Y     1508
#define OFF_Z     1828
#define OFF_G     2148
#define OFF_CTOP  2454
#define OFF_ATOPT 2470
#define OFF_M2    2790
#define LDSZ      2792

__device__ __forceinline__ void slot_to_rq(int s, int& r, int& q) {
  // lower-tri 4-col strips: rows 4w..4w+3 have w+1 strips; row 32 has 9.
  if      (s < 4)   { r = s;               q = 0;    }
  else if (s < 12)  { int i=s-4;   r=4 +i/2; q=i-(i/2)*2; }
  else if (s < 24)  { int i=s-12;  r=8 +i/3; q=i-(i/3)*3; }
  else if (s < 40)  { int i=s-24;  r=12+(i>>2); q=i&3; }
  else if (s < 60)  { int i=s-40;  r=16+i/5; q=i-(i/5)*5; }
  else if (s < 84)  { int i=s-60;  r=20+i/6; q=i-(i/6)*6; }
  else if (s < 112) { int i=s-84;  r=24+i/7; q=i-(i/7)*7; }
  else if (s < 144) { int i=s-112; r=28+(i>>3); q=i&7; }
  else              { r = 32; q = s-144; }
}

__global__ __launch_bounds__(128, 7) void cint_kernel(
    const float* __restrict__ input_i,
    const float* __restrict__ Prev_coefs,
    const float* __restrict__ Prev_biases,
    const float* __restrict__ LPin,
    const float* __restrict__ Log_factors,
    const float* __restrict__ obs_var,
    const float* __restrict__ hid_var,
    const float* __restrict__ nxt_var,
    const float* __restrict__ rec_biases,
    float* __restrict__ out,
    int NBP)
{
  __shared__ float lds[LDSZ];

  const int tid  = threadIdx.x;
  const int w    = tid >> 6;
  const int lane = tid & 63;
  const int bid  = blockIdx.x;
  const int inst = (bid & 7) * (NBP >> 3) + (bid >> 3);  // XCD-chunked swizzle

  const size_t NB_OFFv = (size_t)NBP * 256;
  const size_t LP_OFFv = NB_OFFv + (size_t)NBP * 16;

  const float lp_lf = LPin[inst] + Log_factors[inst];

  // ---------------- P0: stage X = [A | B | c]; w0->A(+ATOPT), w1->B/c -------
  {
    const int g = lane;
    const size_t rowidx = (g < 16) ? ((size_t)g * NBP + inst)
                                   : ((size_t)(g - 16) * NBP + inst);
    if (w == 0) {
      const float* aptr = (g < 16) ? (Prev_coefs + rowidx * 16)
                                   : (hid_var    + rowidx * 16);
      float4 a0 = *(const float4*)(aptr + 0);
      float4 a1 = *(const float4*)(aptr + 4);
      float4 a2 = *(const float4*)(aptr + 8);
      float4 a3 = *(const float4*)(aptr + 12);
      *(float4*)&lds[g*36 +  0] = a0;
      *(float4*)&lds[g*36 +  4] = a1;
      *(float4*)&lds[g*36 +  8] = a2;
      *(float4*)&lds[g*36 + 12] = a3;
      if (g < 16) {  // A_top^T stash (outside X region; coalesced per m)
        lds[OFF_ATOPT +  0*20+g]=a0.x; lds[OFF_ATOPT +  1*20+g]=a0.y;
        lds[OFF_ATOPT +  2*20+g]=a0.z; lds[OFF_ATOPT +  3*20+g]=a0.w;
        lds[OFF_ATOPT +  4*20+g]=a1.x; lds[OFF_ATOPT +  5*20+g]=a1.y;
        lds[OFF_ATOPT +  6*20+g]=a1.z; lds[OFF_ATOPT +  7*20+g]=a1.w;
        lds[OFF_ATOPT +  8*20+g]=a2.x; lds[OFF_ATOPT +  9*20+g]=a2.y;
        lds[OFF_ATOPT + 10*20+g]=a2.z; lds[OFF_ATOPT + 11*20+g]=a2.w;
        lds[OFF_ATOPT + 12*20+g]=a3.x; lds[OFF_ATOPT + 13*20+g]=a3.y;
        lds[OFF_ATOPT + 14*20+g]=a3.z; lds[OFF_ATOPT + 15*20+g]=a3.w;
      }
    } else {
      float4 z4 = make_float4(0.f, 0.f, 0.f, 0.f);
      float4 b0 = z4, b1 = z4, b2 = z4, b3 = z4;
      float cv;
      if (g < 16) {
        cv = Prev_biases[rowidx];
        lds[OFF_CTOP + g] = cv;
      } else {
        const float* bptr = nxt_var + rowidx * 16;
        b0 = *(const float4*)(bptr + 0);
        b1 = *(const float4*)(bptr + 4);
        b2 = *(const float4*)(bptr + 8);
        b3 = *(const float4*)(bptr + 12);
        float4 ob = *(const float4*)(obs_var + rowidx * 4);
        float4 iv = *(const float4*)(input_i + (size_t)inst * 4);
        cv = rec_biases[rowidx] + ob.x*iv.x + ob.y*iv.y + ob.z*iv.z + ob.w*iv.w;
      }
      *(float4*)&lds[g*36 + 16] = b0;
      *(float4*)&lds[g*36 + 20] = b1;
      *(float4*)&lds[g*36 + 24] = b2;
      *(float4*)&lds[g*36 + 28] = b3;
      lds[g*36 + 32] = cv;
      lds[g*36 + 33] = 0.f; lds[g*36 + 34] = 0.f; lds[g*36 + 35] = 0.f;
    }
  }
  __syncthreads();

  // ------- P1': Gram M33 lower-tri (153 strips). slot0=tid; extra 25 on w1 --
  int r0, q0; slot_to_rq(tid, r0, q0);
  float a00=0,a01=0,a02=0,a03=0;
  {
    #pragma unroll 8
    for (int g = 0; g < 64; ++g) {
      const float* xr = &lds[g*36];
      float  xi = xr[r0];
      float4 cv = *(const float4*)(xr + 4*q0);
      a00=fmaf(xi,cv.x,a00); a01=fmaf(xi,cv.y,a01);
      a02=fmaf(xi,cv.z,a02); a03=fmaf(xi,cv.w,a03);
    }
  }
  const bool has2 = (tid >= 103);            // wave1 takes slots 128..152
  int r1=0, q1=0;
  float a10=0,a11=0,a12=0,a13=0;
  if (has2) {
    slot_to_rq(tid + 25, r1, q1);
    #pragma unroll 8
    for (int g = 0; g < 64; ++g) {
      const float* xr = &lds[g*36];
      float  xi = xr[r1];
      float4 cv = *(const float4*)(xr + 4*q1);
      a10=fmaf(xi,cv.x,a10); a11=fmaf(xi,cv.y,a11);
      a12=fmaf(xi,cv.z,a12); a13=fmaf(xi,cv.w,a13);
    }
  }
  __syncthreads();   // all X reads done; X dead -> overlay writes allowed

  {
    float4 v0 = make_float4(a00,a01,a02,a03);
    *(float4*)&lds[OFF_M33 + r0*36 + 4*q0] = v0;
    if (r0 >= 16 && q0 < 4) {
      const int k = r0 - 16;
      lds[OFF_STAB + (4*q0+0)*20 + k] = a00;
      lds[OFF_STAB + (4*q0+1)*20 + k] = a01;
      lds[OFF_STAB + (4*q0+2)*20 + k] = a02;
      lds[OFF_STAB + (4*q0+3)*20 + k] = a03;
    }
    if (has2) {
      float4 v1 = make_float4(a10,a11,a12,a13);
      *(float4*)&lds[OFF_M33 + r1*36 + 4*q1] = v1;
      if (r1 >= 16 && q1 < 4) {
        const int k = r1 - 16;
        lds[OFF_STAB + (4*q1+0)*20 + k] = a10;
        lds[OFF_STAB + (4*q1+1)*20 + k] = a11;
        lds[OFF_STAB + (4*q1+2)*20 + k] = a12;
        lds[OFF_STAB + (4*q1+3)*20 + k] = a13;
      }
    }
  }
  __syncthreads();

  // ------- P2: (wave0) Cholesky of S_AA + ONE forward solve, 33 RHS --------
  if (w == 0) {
    float Lr[16];
    {
      const int ir = lane & 15;
      double prodd = 1.0;
      #pragma unroll
      for (int j = 0; j < 16; ++j) {
        // symmetric read: lower triangle only is stored
        float s = lds[OFF_M33 + ((ir >= j) ? (ir*36 + j) : (j*36 + ir))];
        #pragma unroll
        for (int m = 0; m < j; ++m) s = fmaf(-Lr[m], rl32(Lr[m], j), s);
        float sj = fmaxf(rl32(s, j), 1e-30f);
        float Ljj = sqrtf(sj);
        float iv  = 1.0f / Ljj;
        prodd *= (double)sj;
        Lr[j] = (ir == j) ? Ljj : s * iv;
        if (lane == j) lds[OFF_M33 + j*36 + 33] = iv;   // stash 1/L_jj
      }
      if (lane == 0) lds[OFF_M2 + 1] = (float)(-0.5 * log(prodd));  // LC1
    }
    {
      const bool isY = (lane < 17);
      const int  ci  = isY ? lane : ((lane - 17 < 15) ? lane - 17 : 15);
      const float* ip = isY ? &lds[OFF_STAB + ci] : &lds[OFF_ATOPT + ci];
      float x[16];
      #pragma unroll
      for (int j = 0; j < 16; ++j) {
        float t = ip[j*20];
        #pragma unroll
        for (int m = 0; m < j; ++m) t = fmaf(-rl32(Lr[m], j), x[m], t);
        x[j] = t * lds[OFF_M33 + j*36 + 33];
      }
      if (lane < 33) {
        float* op = isY ? &lds[OFF_Y + ci] : &lds[OFF_Z + ci];
        #pragma unroll
        for (int m = 0; m < 16; ++m) op[m*20] = x[m];
      }
    }
  }
  __syncthreads();

  // ------- P3': Ghat = S_BBc - Y^T Y (153 tri entries, mirrored) -----------
  //         and  T = [0|c_top] - Z^T Y  (16x17)
  for (int s = tid; s < 153; s += 128) {
    float fs = 8.f * (float)s + 1.f;
    int k = (int)((sqrtf(fs) - 1.f) * 0.5f);
    int l = s - ((k * (k + 1)) >> 1);
    float acc = lds[OFF_M33 + (16 + k)*36 + 16 + l];
    #pragma unroll
    for (int m = 0; m < 16; ++m)
      acc = fmaf(-lds[OFF_Y + m*20 + k], lds[OFF_Y + m*20 + l], acc);
    lds[OFF_G + k*18 + l] = acc;
    lds[OFF_G + l*18 + k] = acc;
  }
  {
    #pragma unroll
    for (int p = 0; p < 4; ++p) {
      int s = p * 128 + tid;           // 16 rows x 32-slot stride; kk<17 valid
      int r  = s >> 5;
      int kk = s & 31;
      if (kk < 17) {
        float acc = (kk == 16) ? lds[OFF_CTOP + r] : 0.f;
        #pragma unroll
        for (int m = 0; m < 16; ++m)
          acc = fmaf(-lds[OFF_Z + m*20 + r], lds[OFF_Y + m*20 + kk], acc);
        lds[OFF_T + r*20 + kk] = acc;
      }
    }
  }
  __syncthreads();

  // ---------------- P5 (wave0): compressed Householder QR2 (signs) ---------
  if (w == 0) {
    const int k  = lane;
    const int kc = (k < 17) ? k : 16;   // lane k owns column k (16 = Pc)
    float Tr[16];
    float Gh[16];
    #pragma unroll
    for (int r = 0; r < 16; ++r) Tr[r] = lds[OFF_T + r*20 + kc];
    #pragma unroll
    for (int j = 0; j < 16; ++j) Gh[j] = lds[OFF_G + j*18 + kc];
    float nbacc = 0.0f;
    #pragma unroll
    for (int j = 0; j < 16; ++j) {
      float alf  = rl32(Tr[j], j);           // alpha = T[j][j]
      float nrm2 = rl32(Gh[j], j);           // ||active col j||^2
      float nrm  = sqrtf(fmaxf(nrm2, 1e-30f));
      float aa   = fabsf(alf);
      float tau  = 1.0f + aa / nrm;          // (beta-alpha)/beta
      float inv  = copysignf(1.0f / (aa + nrm), alf);  // 1/(alpha-beta)
      float beta = -copysignf(nrm, alf);     // LAPACK R_jj
      float Tj   = Tr[j];
      float wv   = Tj + (Gh[j] - alf * Tj) * inv;      // v^T col_k
      float Rv   = Tj - tau * wv;                      // R[j][k], k>=j
      if (k < 16) {
        float ov = (k < j) ? 0.0f : ((k == j) ? beta : Rv);
        out[((size_t)j * NBP + inst) * 16 + k] = ov;   // Next_coefs
      } else if (k == 16) {
        out[NB_OFFv + (size_t)j * NBP + inst] = Rv;    // Next_biases
        nbacc = fmaf(Rv, Rv, nbacc);
      }
      float twi = tau * wv * inv;
      #pragma unroll
      for (int r = j + 1; r < 16; ++r) {     // T update (rows > j)
        float vr = rl32(Tr[r], j);
        Tr[r] = fmaf(-twi, vr, Tr[r]);
      }
      #pragma unroll
      for (int l = j + 1; l < 16; ++l) {     // Ghat -= R_j outer R_j
        float Rl = rl32(Rv, l);
        Gh[l] = fmaf(-Rl, Rv, Gh[l]);
      }
    }
    if (k == 16) {
      double resid = fmax((double)lds[OFF_G + 16*18 + 16] - (double)nbacc, 0.0);
      double LC = (double)lds[OFF_M2 + 1] - 0.5 * (32.0 * LOG2PI + resid);
      out[LP_OFFv + (size_t)inst] = lp_lf + (float)LC;
    }
  }
}

extern "C" void kernel_launch(void* const* d_in, const int* in_sizes, int n_in,
                              void* d_out, int out_size, void* d_ws, size_t ws_size,
                              hipStream_t stream) {
  (void)n_in; (void)out_size; (void)d_ws; (void)ws_size;
  const int NBP = in_sizes[3];              // B*P (LP element count) = 8192
  cint_kernel<<<NBP, 128, 0, stream>>>(
      (const float*)d_in[0], (const float*)d_in[1], (const float*)d_in[2],
      (const float*)d_in[3], (const float*)d_in[4], (const float*)d_in[5],
      (const float*)d_in[6], (const float*)d_in[7], (const float*)d_in[8],
      (float*)d_out, NBP);
}

// Round 10
// 169.870 us; speedup vs baseline: 1.0973x; 1.0417x over previous
//
#include <hip/hip_runtime.h>

#define LOG2PI 1.8378770664093453

__device__ __forceinline__ float rl32(float v, int l) {
  return __int_as_float(__builtin_amdgcn_readlane(__float_as_int(v), l));
}

// ONE WAVE = ONE INSTANCE, ZERO BARRIERS. 64-thread blocks, 14 blocks/CU.
// r9 finding: serial phases (chol/solve/P5) on wave0 while wave1 idled at
// barriers capped VALUBusy at 62%. Now every resident wave runs the full
// pipeline; wave-lockstep provides all intra-wave LDS ordering for free.
//   P1: Gram M33 = [A|B|c]^T[A|B|c] lower-tri, 153 4-col strips, 3 fused rounds
//   P2: chol(S_AA) + ONE forward solve, 33 RHS (Y = L\S_ABc, Z = L\A_top^T)
//   P3: Ghat = S_BBc - Y^T Y  (in-place in M33's SBBc block, mirrored)
//   P4: T = [0|c_top] - Z^T Y (overlays dead S_AA rows)
//   P5: compressed Householder sign recursion (LAPACK beta=-sign(alpha)*nrm)
// LDS overlays (floats): X[64][36] at 0; M33 row m at 1116+m*36 (X rows 31..63;
// A_top/c_top live in X rows 0..15); 1/Ljj stash col33 rows0..15 of M33; LC1 at
// 1116+34; Y[16][17] at 2304; Z[16][17] at 2576. Total 2848 fl = 11392 B.
#define MO   1116
#define YO   2304
#define ZO   2576
#define LC1O (MO + 34)
#define WSZ  2848

__device__ __forceinline__ void slot_to_rq(int s, int& r, int& q) {
  // lower-tri 4-col strips: rows 4w..4w+3 have w+1 strips; row 32 has 9.
  if      (s < 4)   { r = s;               q = 0;    }
  else if (s < 12)  { int i=s-4;   r=4 +i/2; q=i-(i/2)*2; }
  else if (s < 24)  { int i=s-12;  r=8 +i/3; q=i-(i/3)*3; }
  else if (s < 40)  { int i=s-24;  r=12+(i>>2); q=i&3; }
  else if (s < 60)  { int i=s-40;  r=16+i/5; q=i-(i/5)*5; }
  else if (s < 84)  { int i=s-60;  r=20+i/6; q=i-(i/6)*6; }
  else if (s < 112) { int i=s-84;  r=24+i/7; q=i-(i/7)*7; }
  else if (s < 144) { int i=s-112; r=28+(i>>3); q=i&7; }
  else              { r = 32; q = s-144; }
}

__global__ __launch_bounds__(64, 4) void cint_kernel(
    const float* __restrict__ input_i,
    const float* __restrict__ Prev_coefs,
    const float* __restrict__ Prev_biases,
    const float* __restrict__ LPin,
    const float* __restrict__ Log_factors,
    const float* __restrict__ obs_var,
    const float* __restrict__ hid_var,
    const float* __restrict__ nxt_var,
    const float* __restrict__ rec_biases,
    float* __restrict__ out,
    int NBP)
{
  __shared__ float L[WSZ];

  const int lane = threadIdx.x;
  const int bid  = blockIdx.x;
  const int inst = (bid & 7) * (NBP >> 3) + (bid >> 3);  // XCD-chunked swizzle

  const size_t NB_OFFv = (size_t)NBP * 256;
  const size_t LP_OFFv = NB_OFFv + (size_t)NBP * 16;

  const float lp_lf = LPin[inst] + Log_factors[inst];

  // ---------------- P0: stage X rows; cols 33..35 zeroed -------------------
  {
    const int g = lane;
    const size_t rowidx = ((size_t)(g < 16 ? g : g - 16)) * NBP + inst;
    const float4 z4 = make_float4(0.f, 0.f, 0.f, 0.f);
    if (g < 16) {
      const float* aptr = Prev_coefs + rowidx * 16;
      *(float4*)&L[g*36 +  0] = *(const float4*)(aptr + 0);
      *(float4*)&L[g*36 +  4] = *(const float4*)(aptr + 4);
      *(float4*)&L[g*36 +  8] = *(const float4*)(aptr + 8);
      *(float4*)&L[g*36 + 12] = *(const float4*)(aptr + 12);
      *(float4*)&L[g*36 + 16] = z4;
      *(float4*)&L[g*36 + 20] = z4;
      *(float4*)&L[g*36 + 24] = z4;
      *(float4*)&L[g*36 + 28] = z4;
      float c = Prev_biases[rowidx];
      *(float4*)&L[g*36 + 32] = make_float4(c, 0.f, 0.f, 0.f);
    } else {
      const float* aptr = hid_var + rowidx * 16;
      *(float4*)&L[g*36 +  0] = *(const float4*)(aptr + 0);
      *(float4*)&L[g*36 +  4] = *(const float4*)(aptr + 4);
      *(float4*)&L[g*36 +  8] = *(const float4*)(aptr + 8);
      *(float4*)&L[g*36 + 12] = *(const float4*)(aptr + 12);
      const float* bptr = nxt_var + rowidx * 16;
      *(float4*)&L[g*36 + 16] = *(const float4*)(bptr + 0);
      *(float4*)&L[g*36 + 20] = *(const float4*)(bptr + 4);
      *(float4*)&L[g*36 + 24] = *(const float4*)(bptr + 8);
      *(float4*)&L[g*36 + 28] = *(const float4*)(bptr + 12);
      float4 ob = *(const float4*)(obs_var + rowidx * 4);
      float4 iv = *(const float4*)(input_i + (size_t)inst * 4);
      float c = rec_biases[rowidx] + ob.x*iv.x + ob.y*iv.y + ob.z*iv.z + ob.w*iv.w;
      *(float4*)&L[g*36 + 32] = make_float4(c, 0.f, 0.f, 0.f);
    }
  }

  // ---------------- P1: Gram, 153 strips over 64 lanes, fused 3-round loop -
  {
    int r0,q0,r1,q1,r2,q2;
    slot_to_rq(lane,      r0, q0);
    slot_to_rq(lane + 64, r1, q1);
    const bool h3 = (lane < 25);
    slot_to_rq(h3 ? lane + 128 : 152, r2, q2);
    float a00=0,a01=0,a02=0,a03=0;
    float a10=0,a11=0,a12=0,a13=0;
    float a20=0,a21=0,a22=0,a23=0;
    #pragma unroll 4
    for (int g = 0; g < 64; ++g) {
      const float* xr = &L[g*36];
      float  x0 = xr[r0]; float4 v0 = *(const float4*)(xr + 4*q0);
      float  x1 = xr[r1]; float4 v1 = *(const float4*)(xr + 4*q1);
      float  x2 = xr[r2]; float4 v2 = *(const float4*)(xr + 4*q2);
      a00=fmaf(x0,v0.x,a00); a01=fmaf(x0,v0.y,a01);
      a02=fmaf(x0,v0.z,a02); a03=fmaf(x0,v0.w,a03);
      a10=fmaf(x1,v1.x,a10); a11=fmaf(x1,v1.y,a11);
      a12=fmaf(x1,v1.z,a12); a13=fmaf(x1,v1.w,a13);
      a20=fmaf(x2,v2.x,a20); a21=fmaf(x2,v2.y,a21);
      a22=fmaf(x2,v2.z,a22); a23=fmaf(x2,v2.w,a23);
    }
    // all X reads done; M33 overlays X rows 31..63 (A_top rows 0..15 stay)
    *(float4*)&L[MO + r0*36 + 4*q0] = make_float4(a00,a01,a02,a03);
    *(float4*)&L[MO + r1*36 + 4*q1] = make_float4(a10,a11,a12,a13);
    if (h3)
      *(float4*)&L[MO + r2*36 + 4*q2] = make_float4(a20,a21,a22,a23);
  }

  // ---------------- P2a: Cholesky of S_AA (16 row-lanes; others duplicate) -
  float Lr[16];
  {
    const int ir = lane & 15;
    double prodd = 1.0;
    #pragma unroll
    for (int j = 0; j < 16; ++j) {
      float s = L[MO + ((ir >= j) ? (ir*36 + j) : (j*36 + ir))];
      #pragma unroll
      for (int m = 0; m < j; ++m) s = fmaf(-Lr[m], rl32(Lr[m], j), s);
      float sj = fmaxf(rl32(s, j), 1e-30f);
      float Ljj = sqrtf(sj);
      float iv  = 1.0f / Ljj;
      prodd *= (double)sj;
      Lr[j] = (ir == j) ? Ljj : s * iv;
      if (lane == j) L[MO + j*36 + 33] = iv;   // stash 1/L_jj
    }
    if (lane == 0) L[LC1O] = (float)(-0.5 * log(prodd));  // LC1
  }

  // ---------------- P2b: ONE forward solve, 33 RHS (Y | Z) -----------------
  {
    const bool isY = (lane < 17);
    const int  ci  = isY ? lane : ((lane - 17 < 15) ? lane - 17 : 15);
    float x[16];
    #pragma unroll
    for (int j = 0; j < 16; ++j) {
      // RHS: Y-col k: S_ABc[j][k] = M33[16+k][j]; Z-col r: A_top[r][j] = X[r][j]
      float t = isY ? L[MO + (16 + ci)*36 + j] : L[ci*36 + j];
      #pragma unroll
      for (int m = 0; m < j; ++m) t = fmaf(-rl32(Lr[m], j), x[m], t);
      x[j] = t * L[MO + j*36 + 33];
    }
    if (lane < 33) {
      float* op = isY ? &L[YO + ci] : &L[ZO + ci];
      #pragma unroll
      for (int m = 0; m < 16; ++m) op[m*17] = x[m];
    }
  }

  // ---------------- P3: Ghat = S_BBc - Y^T Y, IN-PLACE in M33 SBBc ---------
  for (int s = lane; s < 153; s += 64) {
    float fs = 8.f * (float)s + 1.f;
    int k = (int)((sqrtf(fs) - 1.f) * 0.5f);
    int l = s - ((k * (k + 1)) >> 1);
    float acc = L[MO + (16 + k)*36 + 16 + l];
    #pragma unroll
    for (int m = 0; m < 16; ++m)
      acc = fmaf(-L[YO + m*17 + k], L[YO + m*17 + l], acc);
    L[MO + (16 + k)*36 + 16 + l] = acc;      // tri slot (read-once, own-write)
    L[MO + (16 + l)*36 + 16 + k] = acc;      // mirror (never a source)
  }

  // ---------------- P4: T = [0|c_top] - Z^T Y (overlays dead S_AA rows) ----
  for (int s = lane; s < 272; s += 64) {
    int r = s / 17;
    int k = s - r * 17;
    float acc = (k == 16) ? L[r*36 + 32] : 0.f;   // c_top from live X rows
    #pragma unroll
    for (int m = 0; m < 16; ++m)
      acc = fmaf(-L[ZO + m*17 + r], L[YO + m*17 + k], acc);
    L[MO + r*36 + k] = acc;
  }

  // ---------------- P5: compressed Householder QR2 (LAPACK signs) ----------
  {
    const int k  = lane;
    const int kc = (k < 17) ? k : 16;   // lane k owns column k (16 = Pc)
    float Tr[16];
    float Gh[16];
    #pragma unroll
    for (int r = 0; r < 16; ++r) Tr[r] = L[MO + r*36 + kc];
    #pragma unroll
    for (int j = 0; j < 16; ++j) Gh[j] = L[MO + (16 + j)*36 + 16 + kc];
    float nbacc = 0.0f;
    #pragma unroll
    for (int j = 0; j < 16; ++j) {
      float alf  = rl32(Tr[j], j);           // alpha = T[j][j]
      float nrm2 = rl32(Gh[j], j);           // ||active col j||^2
      float nrm  = sqrtf(fmaxf(nrm2, 1e-30f));
      float aa   = fabsf(alf);
      float tau  = 1.0f + aa / nrm;          // (beta-alpha)/beta
      float inv  = copysignf(1.0f / (aa + nrm), alf);  // 1/(alpha-beta)
      float beta = -copysignf(nrm, alf);     // LAPACK R_jj
      float Tj   = Tr[j];
      float wv   = Tj + (Gh[j] - alf * Tj) * inv;      // v^T col_k
      float Rv   = Tj - tau * wv;                      // R[j][k], k>=j
      if (k < 16) {
        float ov = (k < j) ? 0.0f : ((k == j) ? beta : Rv);
        out[((size_t)j * NBP + inst) * 16 + k] = ov;   // Next_coefs
      } else if (k == 16) {
        out[NB_OFFv + (size_t)j * NBP + inst] = Rv;    // Next_biases
        nbacc = fmaf(Rv, Rv, nbacc);
      }
      float twi = tau * wv * inv;
      #pragma unroll
      for (int r = j + 1; r < 16; ++r) {     // T update (rows > j)
        float vr = rl32(Tr[r], j);
        Tr[r] = fmaf(-twi, vr, Tr[r]);
      }
      #pragma unroll
      for (int l = j + 1; l < 16; ++l) {     // Ghat -= R_j outer R_j
        float Rl = rl32(Rv, l);
        Gh[l] = fmaf(-Rl, Rv, Gh[l]);
      }
    }
    if (k == 16) {
      double resid = fmax((double)L[MO + 32*36 + 32] - (double)nbacc, 0.0);
      double LC = (double)L[LC1O] - 0.5 * (32.0 * LOG2PI + resid);
      out[LP_OFFv + (size_t)inst] = lp_lf + (float)LC;
    }
  }
}

extern "C" void kernel_launch(void* const* d_in, const int* in_sizes, int n_in,
                              void* d_out, int out_size, void* d_ws, size_t ws_size,
                              hipStream_t stream) {
  (void)n_in; (void)out_size; (void)d_ws; (void)ws_size;
  const int NBP = in_sizes[3];              // B*P (LP element count) = 8192
  cint_kernel<<<NBP, 64, 0, stream>>>(
      (const float*)d_in[0], (const float*)d_in[1], (const float*)d_in[2],
      (const float*)d_in[3], (const float*)d_in[4], (const float*)d_in[5],
      (const float*)d_in[6], (const float*)d_in[7], (const float*)d_in[8],
      (float*)d_out, NBP);
}